// Round 12
// baseline (490.458 us; speedup 1.0000x reference)
//
#include <hip/hip_runtime.h>

#define NN 100000
#define NE 1600000
#define NG 1024
#define DIN 128
#define D1 100
#define D2 20
#define DSELF 16
#define BN_EPS 1e-5f

#define NB 391      // node buckets of 256 nodes
#define NBLK 782    // edge slice blocks (2048 edges each)
#define EPB 2048
#define RAWCAP 5120 // max edges per bucket (mean 4096, +16 sigma)
#define NAGG2 4000  // agg2 blocks (25 nodes each)
#define APITCH 136  // gemm1 LDS row pitch (bf16)

typedef unsigned int uint;
typedef unsigned short ushort;
typedef __attribute__((ext_vector_type(8))) short bfv8;
typedef __attribute__((ext_vector_type(4))) float fv4;

__device__ inline float bflo(uint x) { return __uint_as_float(x << 16); }
__device__ inline float bfhi(uint x) { return __uint_as_float(x & 0xffff0000u); }
__device__ inline uint packbf2(float a, float b) {  // round-nearest-even bf16 pair
    uint ua = __float_as_uint(a), ub = __float_as_uint(b);
    ua += 0x7fffu + ((ua >> 16) & 1u);
    ub += 0x7fffu + ((ub >> 16) & 1u);
    return (ua >> 16) | (ub & 0xffff0000u);
}
__device__ inline ushort bfr(float x) {
    uint u = __float_as_uint(x);
    u += 0x7fffu + ((u >> 16) & 1u);
    return (ushort)(u >> 16);
}

// ------- z1bf = bf16(feat @ W1) via MFMA 16x16x32 bf16 (standalone) ---------
__global__ __launch_bounds__(256) void k_gemm1(const float* __restrict__ feat,
                                               const float* __restrict__ W1,
                                               ushort* __restrict__ z1bf) {
    __shared__ __align__(16) char smem[64 * APITCH * 2 + 112 * APITCH * 2];
    ushort* Al = (ushort*)smem;
    ushort* Bt = (ushort*)(smem + 64 * APITCH * 2);
    int t = threadIdx.x;
    int row0 = blockIdx.x * 64;
#pragma unroll
    for (int i = 0; i < 8; i++) {
        int p = i * 256 + t;
        int r = p >> 5, cq = p & 31;
        int row = row0 + r; if (row >= NN) row = NN - 1;
        float4 v = *(const float4*)(feat + (size_t)row * DIN + cq * 4);
        ushort* dst = Al + r * APITCH + 4 * cq;
        dst[0] = bfr(v.x); dst[1] = bfr(v.y); dst[2] = bfr(v.z); dst[3] = bfr(v.w);
    }
    for (int p = t; p < 12800; p += 256) {
        int k = p / 100, n = p % 100;
        Bt[n * APITCH + k] = bfr(W1[p]);
    }
    __syncthreads();
    int w = __builtin_amdgcn_readfirstlane(t >> 6);
    int l = t & 63;
    int m16 = l & 15, quad = l >> 4;
    fv4 acc[7];
#pragma unroll
    for (int nt = 0; nt < 7; nt++) acc[nt] = (fv4){0.f, 0.f, 0.f, 0.f};
    const ushort* arow = Al + (w * 16 + m16) * APITCH;
#pragma unroll
    for (int kk = 0; kk < 4; kk++) {
        int kb = kk * 32 + quad * 8;
        bfv8 a = *(const bfv8*)(arow + kb);
#pragma unroll
        for (int nt = 0; nt < 7; nt++) {
            bfv8 b = *(const bfv8*)(Bt + (nt * 16 + m16) * APITCH + kb);
            acc[nt] = __builtin_amdgcn_mfma_f32_16x16x32_bf16(a, b, acc[nt], 0, 0, 0);
        }
    }
    __syncthreads();
    float* Ep = (float*)smem;
#pragma unroll
    for (int nt = 0; nt < 7; nt++) {
        int n = nt * 16 + m16;
        if (n < 100) {
#pragma unroll
            for (int rix = 0; rix < 4; rix++)
                Ep[(w * 16 + quad * 4 + rix) * 101 + n] = acc[nt][rix];
        }
    }
    __syncthreads();
#pragma unroll
    for (int i = 0; i < 13; i++) {
        int p = i * 256 + t;
        if (p < 3200) {
            int rr = p / 50, cc = 2 * (p % 50);
            int row = row0 + rr;
            if (row < NN) {
                float v0 = Ep[rr * 101 + cc], v1 = Ep[rr * 101 + cc + 1];
                *(uint*)(z1bf + (size_t)row * 128 + cc) = packbf2(v0, v1);
            }
        }
    }
}

// A1: per-(bucket,block) histogram (standalone, small LDS -> high occupancy)
__global__ __launch_bounds__(256) void k_csrA1(const int* __restrict__ dst,
                                               int* __restrict__ pbcount) {
    __shared__ int h[NB];
    int t = threadIdx.x, blk = blockIdx.x;
    for (int i = t; i < NB; i += 256) h[i] = 0;
    __syncthreads();
    int e0 = blk * EPB + t;
#pragma unroll
    for (int i = 0; i < 8; i++) {
        int e = e0 + i * 256;
        if (e < NE) atomicAdd(&h[dst[e] >> 8], 1);
    }
    __syncthreads();
    for (int i = t; i < NB; i += 256) pbcount[i * NBLK + blk] = h[i];
}

// S1: per-bucket exclusive scan over 782 blocks (in-place) + bucket totals
__global__ __launch_bounds__(1024) void k_csrS1(int* __restrict__ pbcount,
                                                int* __restrict__ btot) {
    __shared__ int s[1024];
    int t = threadIdx.x, b = blockIdx.x;
    int v = (t < NBLK) ? pbcount[b * NBLK + t] : 0;
    s[t] = v;
    __syncthreads();
    for (int off = 1; off < 1024; off <<= 1) {
        int x = (t >= off) ? s[t - off] : 0;
        __syncthreads();
        s[t] += x;
        __syncthreads();
    }
    if (t < NBLK) pbcount[b * NBLK + t] = s[t] - v;
    if (t == 1023) btot[b] = s[t];
}

// A2: in-block ebase scan of btot; append packed edges; blk 0 publishes ebase
__global__ __launch_bounds__(256) void k_csrA2(const int* __restrict__ src,
                                               const int* __restrict__ dst,
                                               const int* __restrict__ pbexcl,
                                               const int* __restrict__ btot,
                                               int* __restrict__ ebase_g,
                                               uint* __restrict__ gbuf) {
    __shared__ int cur[NB];
    __shared__ int sa[512], sb[512];
    int t = threadIdx.x, blk = blockIdx.x;
    int o0 = (t < NB) ? btot[t] : 0;
    int o1 = (t + 256 < NB) ? btot[t + 256] : 0;
    sa[t] = o0; sa[t + 256] = o1;
    __syncthreads();
    int* sp = sa; int* dp = sb;
    for (int off = 1; off < 512; off <<= 1) {
        dp[t] = sp[t] + ((t >= off) ? sp[t - off] : 0);
        int i2 = t + 256;
        dp[i2] = sp[i2] + ((i2 >= off) ? sp[i2 - off] : 0);
        __syncthreads();
        int* tmp = sp; sp = dp; dp = tmp;
    }
    if (t < NB)       cur[t]       = (sp[t] - o0) + pbexcl[t * NBLK + blk];
    if (t + 256 < NB) cur[t + 256] = (sp[t + 256] - o1) + pbexcl[(t + 256) * NBLK + blk];
    if (blk == 0) {
        if (t < NB)       ebase_g[t]       = sp[t] - o0;
        if (t + 256 < NB) ebase_g[t + 256] = sp[t + 256] - o1;
        if (t == 0)       ebase_g[NB]      = sp[NB - 1];
    }
    __syncthreads();
    int e0 = blk * EPB + t;
#pragma unroll
    for (int i = 0; i < 8; i++) {
        int e = e0 + i * 256;
        if (e < NE) {
            int d = dst[e];
            int b = d >> 8;
            int pos = atomicAdd(&cur[b], 1);
            gbuf[pos] = (uint)src[e] | ((uint)(d & 255) << 17);
        }
    }
}

// B: per-bucket LDS counting sort by local dst -> deg, offs, srcS (all dense)
__global__ __launch_bounds__(256) void k_csrB(const uint* __restrict__ gbuf,
                                              const int* __restrict__ ebase,
                                              int* __restrict__ deg,
                                              int* __restrict__ offs,
                                              int* __restrict__ srcS) {
    __shared__ uint raw[RAWCAP];
    __shared__ int srt[RAWCAP];
    __shared__ int pref[256], cur[256];
    int t = threadIdx.x, b = blockIdx.x;
    int e0 = ebase[b], e1 = ebase[b + 1];
    int cnt = e1 - e0; if (cnt > RAWCAP) cnt = RAWCAP;
    cur[t] = 0;
    for (int i = t; i < cnt; i += 256) raw[i] = gbuf[e0 + i];
    __syncthreads();
    for (int i = t; i < cnt; i += 256) atomicAdd(&cur[raw[i] >> 17], 1);
    __syncthreads();
    int v = cur[t];
    pref[t] = v;
    __syncthreads();
    for (int off = 1; off < 256; off <<= 1) {
        int x = (t >= off) ? pref[t - off] : 0;
        __syncthreads();
        pref[t] += x;
        __syncthreads();
    }
    int excl = pref[t] - v;
    int node = b * 256 + t;
    if (node < NN) { deg[node] = v; offs[node] = e0 + excl; }
    cur[t] = excl;
    __syncthreads();
    for (int i = t; i < cnt; i += 256) {
        uint p = raw[i];
        int lpos = atomicAdd(&cur[p >> 17], 1);
        srt[lpos] = (int)(p & 0x1FFFFu);
    }
    __syncthreads();
    for (int i = t; i < cnt; i += 256) srcS[e0 + i] = srt[i];
}

// ------- u1(bf16) = z1 + gather-sum; wave/node, unroll 8 --------
__global__ __launch_bounds__(256) void k_agg1(const ushort* __restrict__ z1bf,
                                              const int* __restrict__ offs,
                                              const int* __restrict__ deg,
                                              const int* __restrict__ srcS,
                                              ushort* __restrict__ u1b) {
    int wq = __builtin_amdgcn_readfirstlane(threadIdx.x >> 6);
    int l = threadIdx.x & 63;
    int n = blockIdx.x * 4 + wq;
    if (n >= NN) return;
    int d = deg[n], base = offs[n];
    bool act = l < 50;
    const ushort* zc = z1bf + 2 * l;
    float a0 = 0.f, a1 = 0.f, b0 = 0.f, b1 = 0.f;
    float c0 = 0.f, c1 = 0.f, e0 = 0.f, e1 = 0.f;
    int i = 0;
    for (; i + 8 <= d; i += 8) {
        int s0 = srcS[base + i],     s1 = srcS[base + i + 1];
        int s2 = srcS[base + i + 2], s3 = srcS[base + i + 3];
        int s4 = srcS[base + i + 4], s5 = srcS[base + i + 5];
        int s6 = srcS[base + i + 6], s7 = srcS[base + i + 7];
        if (act) {
            uint x0 = *(const uint*)(zc + (size_t)s0 * 128);
            uint x1 = *(const uint*)(zc + (size_t)s1 * 128);
            uint x2 = *(const uint*)(zc + (size_t)s2 * 128);
            uint x3 = *(const uint*)(zc + (size_t)s3 * 128);
            uint x4 = *(const uint*)(zc + (size_t)s4 * 128);
            uint x5 = *(const uint*)(zc + (size_t)s5 * 128);
            uint x6 = *(const uint*)(zc + (size_t)s6 * 128);
            uint x7 = *(const uint*)(zc + (size_t)s7 * 128);
            a0 += bflo(x0); a1 += bfhi(x0);
            b0 += bflo(x1); b1 += bfhi(x1);
            c0 += bflo(x2); c1 += bfhi(x2);
            e0 += bflo(x3); e1 += bfhi(x3);
            a0 += bflo(x4); a1 += bfhi(x4);
            b0 += bflo(x5); b1 += bfhi(x5);
            c0 += bflo(x6); c1 += bfhi(x6);
            e0 += bflo(x7); e1 += bfhi(x7);
        }
    }
    for (; i + 2 <= d; i += 2) {
        int s0 = srcS[base + i], s1 = srcS[base + i + 1];
        if (act) {
            uint x0 = *(const uint*)(zc + (size_t)s0 * 128);
            uint x1 = *(const uint*)(zc + (size_t)s1 * 128);
            a0 += bflo(x0); a1 += bfhi(x0);
            b0 += bflo(x1); b1 += bfhi(x1);
        }
    }
    if (i < d) {
        int s0 = srcS[base + i];
        if (act) {
            uint x0 = *(const uint*)(zc + (size_t)s0 * 128);
            a0 += bflo(x0); a1 += bfhi(x0);
        }
    }
    if (act) {
        uint xs = *(const uint*)(zc + (size_t)n * 128);
        float r0 = (a0 + b0) + (c0 + e0) + bflo(xs);
        float r1 = (a1 + b1) + (c1 + e1) + bfhi(xs);
        *(uint*)(u1b + (size_t)n * 100 + 2 * l) = packbf2(r0, r1);
    }
}

// ----- BN stats over u1 (bf16 in, 500 block partials) -----
__global__ __launch_bounds__(256) void k_bnstat100(const ushort* __restrict__ u1b,
                                                   float* __restrict__ pb) {
    __shared__ float ls[10][100], lq[10][100];
    int t = threadIdx.x;
    int r0 = blockIdx.x * 200;
    int r1 = r0 + 200; if (r1 > NN) r1 = NN;
    if (t < 250) {
        int sub = t / 25, q = t % 25;
        float4 S = make_float4(0, 0, 0, 0), Q = make_float4(0, 0, 0, 0);
        for (int r = r0 + sub; r < r1; r += 10) {
            uint2 x = *(const uint2*)(u1b + (size_t)r * 100 + 4 * q);
            float v0 = bflo(x.x), v1 = bfhi(x.x), v2 = bflo(x.y), v3 = bfhi(x.y);
            S.x += v0; S.y += v1; S.z += v2; S.w += v3;
            Q.x = fmaf(v0, v0, Q.x); Q.y = fmaf(v1, v1, Q.y);
            Q.z = fmaf(v2, v2, Q.z); Q.w = fmaf(v3, v3, Q.w);
        }
        ls[sub][4 * q + 0] = S.x; ls[sub][4 * q + 1] = S.y;
        ls[sub][4 * q + 2] = S.z; ls[sub][4 * q + 3] = S.w;
        lq[sub][4 * q + 0] = Q.x; lq[sub][4 * q + 1] = Q.y;
        lq[sub][4 * q + 2] = Q.z; lq[sub][4 * q + 3] = Q.w;
    }
    __syncthreads();
    if (t < 100) {
        float S = 0.f, Q = 0.f;
#pragma unroll
        for (int s = 0; s < 10; s++) { S += ls[s][t]; Q += lq[s][t]; }
        pb[blockIdx.x * 200 + t] = S;
        pb[blockIdx.x * 200 + 100 + t] = Q;
    }
}

// fold 500 records + finalize, one block (coalesced)
__global__ __launch_bounds__(1024) void k_bnfin100(const float* __restrict__ pb,
                                                   const float* __restrict__ gamma,
                                                   const float* __restrict__ beta,
                                                   float* __restrict__ sc,
                                                   float* __restrict__ sh) {
    __shared__ float rs[5][200];
    int t = threadIdx.x;
    float acc = 0.f;
    if (t < 1000) {
        int c = t % 200, sub = t / 200;
        for (int b = sub; b < 500; b += 5) acc += pb[b * 200 + c];
        rs[sub][c] = acc;
    }
    __syncthreads();
    if (t < 200) {
        float S = rs[0][t] + rs[1][t] + rs[2][t] + rs[3][t] + rs[4][t];
        rs[0][t] = S;
    }
    __syncthreads();
    if (t < 100) {
        float S = rs[0][t], Q = rs[0][t + 100];
        float mean = S * (1.f / NN);
        float var = Q * (1.f / NN) - mean * mean;
        float inv = rsqrtf(var + BN_EPS);
        float s = gamma[t] * inv;
        sc[t] = s;
        sh[t] = beta[t] - mean * s;
    }
}

// ------ fused: relu(bn1(u1)) @ g1_W2 + b2 -> relu -> @ g2_W1 = z2bf ----------
__global__ __launch_bounds__(256) void k_m2(const ushort* __restrict__ u1b,
                                            const float* __restrict__ sc,
                                            const float* __restrict__ sh,
                                            const float* __restrict__ W2,   // [100][100]
                                            const float* __restrict__ b2,
                                            const float* __restrict__ W1p,  // [100][20]
                                            ushort* __restrict__ z2bf) {
    __shared__ float Xs[100 * 65];
    int t = threadIdx.x;
    int row0 = blockIdx.x * 64;
#pragma unroll
    for (int i = 0; i < 13; i++) {
        int p = i * 256 + t;
        if (p < 3200) {
            int r = p / 50, c = 2 * (p % 50);
            int row = row0 + r; if (row >= NN) row = NN - 1;
            uint x = *(const uint*)(u1b + (size_t)row * 100 + c);
            Xs[c * 65 + r] = fmaxf(bflo(x) * sc[c] + sh[c], 0.f);
            Xs[(c + 1) * 65 + r] = fmaxf(bfhi(x) * sc[c + 1] + sh[c + 1], 0.f);
        }
    }
    __syncthreads();
    int cg = __builtin_amdgcn_readfirstlane(t >> 6);
    int r = t & 63;
    int j0 = cg * 25;
    float H[25];
#pragma unroll
    for (int m = 0; m < 25; m++) H[m] = 0.f;
    for (int k = 0; k < D1; k++) {
        float a = Xs[k * 65 + r];
        const float* wr = W2 + k * D1 + j0;  // wave-uniform -> s_load
#pragma unroll
        for (int m = 0; m < 25; m++) H[m] = fmaf(a, wr[m], H[m]);
    }
#pragma unroll
    for (int m = 0; m < 25; m++) H[m] = fmaxf(H[m] + b2[j0 + m], 0.f);
    float pz[20];
#pragma unroll
    for (int c = 0; c < 20; c++) pz[c] = 0.f;
#pragma unroll
    for (int m = 0; m < 25; m++) {
        const float* wp = W1p + (j0 + m) * D2;  // wave-uniform -> s_load
#pragma unroll
        for (int c = 0; c < 20; c++) pz[c] = fmaf(H[m], wp[c], pz[c]);
    }
    __syncthreads();
    float* red = Xs;
#pragma unroll
    for (int c = 0; c < 20; c++) red[t * 20 + c] = pz[c];
    __syncthreads();
#pragma unroll
    for (int i = 0; i < 3; i++) {
        int p = i * 256 + t;
        if (p < 640) {
            int rr = p / 10, c2 = 2 * (p % 10);
            int row = row0 + rr;
            if (row < NN) {
                float v0 = red[rr * 20 + c2] + red[(64 + rr) * 20 + c2] +
                           red[(128 + rr) * 20 + c2] + red[(192 + rr) * 20 + c2];
                float v1 = red[rr * 20 + c2 + 1] + red[(64 + rr) * 20 + c2 + 1] +
                           red[(128 + rr) * 20 + c2 + 1] + red[(192 + rr) * 20 + c2 + 1];
                *(uint*)(z2bf + (size_t)row * 32 + c2) = packbf2(v0, v1);
            }
        }
    }
}

// ------- u2 = z2 + gather-sum (+ fused BN2 block partials) ---------
__global__ __launch_bounds__(256) void k_agg2(const ushort* __restrict__ z2bf,
                                              const int* __restrict__ offs,
                                              const int* __restrict__ deg,
                                              const int* __restrict__ srcS,
                                              float* __restrict__ u2,
                                              float* __restrict__ pb) {
    __shared__ float ls[500], lq[500];
    int t = threadIdx.x;
    int n = blockIdx.x * 25 + t / 10;
    int c2 = 2 * (t % 10);
    float r0 = 0.f, r1 = 0.f;
    if (t < 250 && n < NN) {
        int d = deg[n], base = offs[n];
        const ushort* zc = z2bf + c2;
        float a0 = 0.f, a1 = 0.f, b0 = 0.f, b1 = 0.f;
        int i = 0;
        for (; i + 2 <= d; i += 2) {
            uint x0 = *(const uint*)(zc + (size_t)srcS[base + i] * 32);
            uint x1 = *(const uint*)(zc + (size_t)srcS[base + i + 1] * 32);
            a0 += bflo(x0); a1 += bfhi(x0);
            b0 += bflo(x1); b1 += bfhi(x1);
        }
        if (i < d) {
            uint x0 = *(const uint*)(zc + (size_t)srcS[base + i] * 32);
            a0 += bflo(x0); a1 += bfhi(x0);
        }
        uint xs = *(const uint*)(zc + (size_t)n * 32);
        r0 = a0 + b0 + bflo(xs);
        r1 = a1 + b1 + bfhi(xs);
        *(float2*)(u2 + (size_t)n * D2 + c2) = make_float2(r0, r1);
    }
    if (t < 250) {
        int idx = (t / 10) * 20 + c2;
        ls[idx] = r0;     lq[idx] = r0 * r0;
        ls[idx + 1] = r1; lq[idx + 1] = r1 * r1;
    }
    __syncthreads();
    if (t < 20) {
        float S = 0.f, Q = 0.f;
#pragma unroll
        for (int j = 0; j < 25; j++) { S += ls[j * 20 + t]; Q += lq[j * 20 + t]; }
        pb[blockIdx.x * 40 + t] = S;
        pb[blockIdx.x * 40 + 20 + t] = Q;
    }
}

// fold 4000 records + finalize, one block (coalesced)
__global__ __launch_bounds__(1024) void k_bnfin20(const float* __restrict__ pb,
                                                  const float* __restrict__ gamma,
                                                  const float* __restrict__ beta,
                                                  float* __restrict__ sc,
                                                  float* __restrict__ sh) {
    __shared__ float rs[25][40];
    int t = threadIdx.x;
    float acc = 0.f;
    if (t < 1000) {
        int c = t % 40, sub = t / 40;
        for (int b = sub; b < NAGG2; b += 25) acc += pb[b * 40 + c];
        rs[sub][c] = acc;
    }
    __syncthreads();
    if (t < 40) {
        float S = 0.f;
#pragma unroll
        for (int s = 0; s < 25; s++) S += rs[s][t];
        rs[0][t] = S;
    }
    __syncthreads();
    if (t < 20) {
        float S = rs[0][t], Q = rs[0][t + 20];
        float mean = S * (1.f / NN);
        float var = Q * (1.f / NN) - mean * mean;
        float inv = rsqrtf(var + BN_EPS);
        float s = gamma[t] * inv;
        sc[t] = s;
        sh[t] = beta[t] - mean * s;
    }
}

// ------ fused: relu(bn2(u2)) @ g2_W2 + b2 -> relu = h2 ------------
__global__ __launch_bounds__(256) void k_m3(const float* __restrict__ u2,
                                            const float* __restrict__ sc,
                                            const float* __restrict__ sh,
                                            const float* __restrict__ W2p,  // [20][20]
                                            const float* __restrict__ b2p,
                                            float* __restrict__ h2) {
    int row = blockIdx.x * 256 + threadIdx.x;
    if (row >= NN) return;
    float ya[20];
    const float4* up = (const float4*)(u2 + (size_t)row * D2);
#pragma unroll
    for (int i = 0; i < 5; i++) {
        float4 v = up[i];
        float4 S = *(const float4*)(sc + 4 * i);
        float4 H = *(const float4*)(sh + 4 * i);
        ya[4 * i + 0] = fmaxf(v.x * S.x + H.x, 0.f);
        ya[4 * i + 1] = fmaxf(v.y * S.y + H.y, 0.f);
        ya[4 * i + 2] = fmaxf(v.z * S.z + H.z, 0.f);
        ya[4 * i + 3] = fmaxf(v.w * S.w + H.w, 0.f);
    }
    float hrow[D2];
#pragma unroll
    for (int j = 0; j < D2; j++) {
        float h = b2p[j];
#pragma unroll
        for (int k = 0; k < D2; k++) h = fmaf(ya[k], W2p[k * D2 + j], h);
        hrow[j] = fmaxf(h, 0.f);
    }
    float* hr = h2 + (size_t)row * D2;
#pragma unroll
    for (int c = 0; c < D2; c += 4) {
        float4 o; o.x = hrow[c]; o.y = hrow[c + 1]; o.z = hrow[c + 2]; o.w = hrow[c + 3];
        *(float4*)(hr + c) = o;
    }
}

// ---- pool: wave/graph, bounds via binary search on sorted n2g ----
__global__ __launch_bounds__(256) void k_pool(const float* __restrict__ h2,
                                              const int* __restrict__ n2g,
                                              float* __restrict__ hg) {
    int wq = __builtin_amdgcn_readfirstlane(threadIdx.x >> 6);
    int l = threadIdx.x & 63;
    int g = blockIdx.x * 4 + wq;
    if (g >= NG) return;
    int lo = 0, hi = NN;
    while (lo < hi) { int mid = (lo + hi) >> 1; if (n2g[mid] < g) lo = mid + 1; else hi = mid; }
    int s0 = lo;
    hi = NN;
    while (lo < hi) { int mid = (lo + hi) >> 1; if (n2g[mid] < g + 1) lo = mid + 1; else hi = mid; }
    int s1 = lo;
    float a = 0.f;
    if (l < 60) {
        int rg = l / 20, c = l % 20;
        for (int n = s0 + rg; n < s1; n += 3) a += h2[(size_t)n * D2 + c];
    }
    float v1 = __shfl(a, l + 20, 64);
    float v2 = __shfl(a, l + 40, 64);
    if (l < 20) {
        float cnt = (float)(s1 - s0);
        hg[g * D2 + l] = (a + v1 + v2) / fmaxf(cnt, 1.f);
    }
}

// ---------------- a1 = kron(hg, self_feat) @ fc1_W ----------------
__global__ void k_head1(const float* __restrict__ hg, const float* __restrict__ sf,
                        const float* __restrict__ fc1W, float* __restrict__ a1) {
    int b = blockIdx.x * 8 + threadIdx.x / 32;
    int c = threadIdx.x % 32;
    if (b >= NG) return;
    const float* hgb = hg + b * D2;
    const float* sfb = sf + b * DSELF;
    float acc = 0.f;
    for (int i = 0; i < D2; i++) {
        float hi = hgb[i];
#pragma unroll
        for (int j = 0; j < DSELF; j++)
            acc += hi * sfb[j] * fc1W[(i * DSELF + j) * 32 + c];
    }
    a1[b * 32 + c] = acc;
}

// ---------------- single-block head: bn1->relu->fc2->bn2->relu->fc3 ----------
__global__ __launch_bounds__(1024) void k_head2(
    const float* __restrict__ a1, const float* __restrict__ g1,
    const float* __restrict__ be1, const float* __restrict__ fc2W,
    const float* __restrict__ g2, const float* __restrict__ be2,
    const float* __restrict__ fc3W, const float* __restrict__ fc3b,
    float* __restrict__ out) {
    int t = threadIdx.x;
    int lane = t & 63, w = t >> 6;
    __shared__ float s1[16][32], s2[16][32];
    __shared__ float sc[32], sh[32], sc2[8], sh2[8];
    float x[32];
    const float4* ap = (const float4*)(a1 + t * 32);
#pragma unroll
    for (int i = 0; i < 8; i++) {
        float4 v = ap[i];
        x[4 * i] = v.x; x[4 * i + 1] = v.y; x[4 * i + 2] = v.z; x[4 * i + 3] = v.w;
    }
#pragma unroll
    for (int c = 0; c < 32; c++) {
        float v = x[c], q = v * v;
        for (int o = 32; o > 0; o >>= 1) {
            v += __shfl_down(v, o, 64);
            q += __shfl_down(q, o, 64);
        }
        if (lane == 0) { s1[w][c] = v; s2[w][c] = q; }
    }
    __syncthreads();
    if (t < 32) {
        float s = 0.f, q = 0.f;
        for (int ww = 0; ww < 16; ww++) { s += s1[ww][t]; q += s2[ww][t]; }
        float mean = s * (1.f / NG);
        float var = q * (1.f / NG) - mean * mean;
        float inv = rsqrtf(var + BN_EPS);
        float scl = g1[t] * inv;
        sc[t] = scl;
        sh[t] = be1[t] - mean * scl;
    }
    __syncthreads();
#pragma unroll
    for (int c = 0; c < 32; c++) x[c] = fmaxf(x[c] * sc[c] + sh[c], 0.f);
    float y[8];
#pragma unroll
    for (int p = 0; p < 8; p++) {
        float a = 0.f;
#pragma unroll
        for (int c = 0; c < 32; c++) a += x[c] * fc2W[c * 8 + p];
        y[p] = a;
    }
    __syncthreads();
#pragma unroll
    for (int p = 0; p < 8; p++) {
        float v = y[p], q = v * v;
        for (int o = 32; o > 0; o >>= 1) {
            v += __shfl_down(v, o, 64);
            q += __shfl_down(q, o, 64);
        }
        if (lane == 0) { s1[w][p] = v; s2[w][p] = q; }
    }
    __syncthreads();
    if (t < 8) {
        float s = 0.f, q = 0.f;
        for (int ww = 0; ww < 16; ww++) { s += s1[ww][t]; q += s2[ww][t]; }
        float mean = s * (1.f / NG);
        float var = q * (1.f / NG) - mean * mean;
        float inv = rsqrtf(var + BN_EPS);
        float scl = g2[t] * inv;
        sc2[t] = scl;
        sh2[t] = be2[t] - mean * scl;
    }
    __syncthreads();
    float o = fc3b[0];
#pragma unroll
    for (int p = 0; p < 8; p++) {
        float yy = fmaxf(y[p] * sc2[p] + sh2[p], 0.f);
        o += yy * fc3W[p];
    }
    out[t] = o;
}

extern "C" void kernel_launch(void* const* d_in, const int* in_sizes, int n_in,
                              void* d_out, int out_size, void* d_ws, size_t ws_size,
                              hipStream_t stream) {
    const float* feat    = (const float*)d_in[0];
    const float* sf      = (const float*)d_in[1];
    const int*   esrc    = (const int*)d_in[2];
    const int*   edst    = (const int*)d_in[3];
    const int*   n2g     = (const int*)d_in[4];
    const float* g1W1    = (const float*)d_in[5];
    const float* g1gam   = (const float*)d_in[7];
    const float* g1bet   = (const float*)d_in[8];
    const float* g1W2    = (const float*)d_in[9];
    const float* g1b2    = (const float*)d_in[10];
    const float* g2W1    = (const float*)d_in[11];
    const float* g2gam   = (const float*)d_in[13];
    const float* g2bet   = (const float*)d_in[14];
    const float* g2W2    = (const float*)d_in[15];
    const float* g2b2    = (const float*)d_in[16];
    const float* fc1W    = (const float*)d_in[17];
    const float* hbn1g   = (const float*)d_in[19];
    const float* hbn1b   = (const float*)d_in[20];
    const float* fc2W    = (const float*)d_in[21];
    const float* hbn2g   = (const float*)d_in[23];
    const float* hbn2b   = (const float*)d_in[24];
    const float* fc3W    = (const float*)d_in[25];
    const float* fc3b    = (const float*)d_in[26];
    float* out = (float*)d_out;

    char* w = (char*)d_ws;
    size_t off = 0;
    auto alloc = [&](size_t bytes) -> char* {
        char* p = w + off;
        off += (bytes + 15) & ~(size_t)15;
        return p;
    };
    char* regA = alloc((size_t)NN * 128 * 2);
    ushort* z1bf = (ushort*)regA;
    ushort* z2bf = (ushort*)regA;
    float*  u2   = (float*)(regA + 6400000);
    float*  h2   = (float*)(regA + 14400000);
    ushort* u1b  = (ushort*)alloc((size_t)NN * 100 * 2);  // bf16 u1, 20 MB
    int*   pbcnt = (int*)alloc((size_t)NB * NBLK * 4);
    int*   btot  = (int*)alloc(NB * 4);
    int*   ebase = (int*)alloc((NB + 1) * 4);
    uint*  gbuf  = (uint*)alloc((size_t)NE * 4);
    int*   deg   = (int*)alloc(NN * 4);
    int*   offs  = (int*)alloc(NN * 4);
    int*   srcS  = (int*)alloc((size_t)NE * 4);
    float* pb1   = (float*)alloc(500 * 200 * 4);
    float* pb2   = (float*)alloc((size_t)NAGG2 * 40 * 4);
    float* sc1   = (float*)alloc(D1 * 4);
    float* sh1   = (float*)alloc(D1 * 4);
    float* sc2   = (float*)alloc(D2 * 4);
    float* sh2   = (float*)alloc(D2 * 4);
    float* hg    = (float*)alloc(NG * D2 * 4);
    float* a1    = (float*)alloc(NG * 32 * 4);
    (void)in_sizes; (void)n_in; (void)out_size; (void)ws_size;

    k_gemm1<<<(NN + 63) / 64, 256, 0, stream>>>(feat, g1W1, z1bf);

    k_csrA1<<<NBLK, 256, 0, stream>>>(edst, pbcnt);
    k_csrS1<<<NB, 1024, 0, stream>>>(pbcnt, btot);
    k_csrA2<<<NBLK, 256, 0, stream>>>(esrc, edst, pbcnt, btot, ebase, gbuf);
    k_csrB<<<NB, 256, 0, stream>>>(gbuf, ebase, deg, offs, srcS);

    k_agg1<<<(NN + 3) / 4, 256, 0, stream>>>(z1bf, offs, deg, srcS, u1b);
    k_bnstat100<<<500, 256, 0, stream>>>(u1b, pb1);
    k_bnfin100<<<1, 1024, 0, stream>>>(pb1, g1gam, g1bet, sc1, sh1);
    k_m2<<<(NN + 63) / 64, 256, 0, stream>>>(u1b, sc1, sh1, g1W2, g1b2, g2W1, z2bf);

    k_agg2<<<NAGG2, 256, 0, stream>>>(z2bf, offs, deg, srcS, u2, pb2);
    k_bnfin20<<<1, 1024, 0, stream>>>(pb2, g2gam, g2bet, sc2, sh2);
    k_m3<<<(NN + 255) / 256, 256, 0, stream>>>(u2, sc2, sh2, g2W2, g2b2, h2);

    k_pool<<<(NG + 3) / 4, 256, 0, stream>>>(h2, n2g, hg);
    k_head1<<<NG / 8, 256, 0, stream>>>(hg, sf, fc1W, a1);
    k_head2<<<1, 1024, 0, stream>>>(a1, hbn1g, hbn1b, fc2W, hbn2g, hbn2b, fc3W, fc3b, out);
}

// Round 13
// 426.030 us; speedup vs baseline: 1.1512x; 1.1512x over previous
//
#include <hip/hip_runtime.h>

#define NN 100000
#define NE 1600000
#define NG 1024
#define DIN 128
#define D1 100
#define D2 20
#define DSELF 16
#define BN_EPS 1e-5f

#define NB 391      // node buckets of 256 nodes
#define NBLK 782    // edge slice blocks (2048 edges each)
#define EPB 2048
#define RAWCAP 5120 // max edges per bucket (mean 4096, +16 sigma)
#define NAGG2 4000  // agg2 blocks (25 nodes each)
#define NF1 25      // folded pb1 records
#define NF2 40      // folded pb2 records
#define APITCH 136  // gemm1 LDS row pitch (bf16)

typedef unsigned int uint;
typedef unsigned short ushort;
typedef __attribute__((ext_vector_type(8))) short bfv8;
typedef __attribute__((ext_vector_type(4))) float fv4;

__device__ inline float bflo(uint x) { return __uint_as_float(x << 16); }
__device__ inline float bfhi(uint x) { return __uint_as_float(x & 0xffff0000u); }
__device__ inline uint packbf2(float a, float b) {  // round-nearest-even bf16 pair
    uint ua = __float_as_uint(a), ub = __float_as_uint(b);
    ua += 0x7fffu + ((ua >> 16) & 1u);
    ub += 0x7fffu + ((ub >> 16) & 1u);
    return (ua >> 16) | (ub & 0xffff0000u);
}
__device__ inline ushort bfr(float x) {
    uint u = __float_as_uint(x);
    u += 0x7fffu + ((u >> 16) & 1u);
    return (ushort)(u >> 16);
}

// ------- z1bf = bf16(feat @ W1) via MFMA 16x16x32 bf16 ---------------------
__global__ __launch_bounds__(256) void k_gemm1(const float* __restrict__ feat,
                                               const float* __restrict__ W1,
                                               ushort* __restrict__ z1bf) {
    __shared__ __align__(16) char smem[64 * APITCH * 2 + 112 * APITCH * 2];
    ushort* Al = (ushort*)smem;
    ushort* Bt = (ushort*)(smem + 64 * APITCH * 2);
    int t = threadIdx.x;
    int row0 = blockIdx.x * 64;
#pragma unroll
    for (int i = 0; i < 8; i++) {
        int p = i * 256 + t;
        int r = p >> 5, cq = p & 31;
        int row = row0 + r; if (row >= NN) row = NN - 1;
        float4 v = *(const float4*)(feat + (size_t)row * DIN + cq * 4);
        ushort* dst = Al + r * APITCH + 4 * cq;
        dst[0] = bfr(v.x); dst[1] = bfr(v.y); dst[2] = bfr(v.z); dst[3] = bfr(v.w);
    }
    for (int p = t; p < 12800; p += 256) {
        int k = p / 100, n = p % 100;
        Bt[n * APITCH + k] = bfr(W1[p]);
    }
    __syncthreads();
    int w = __builtin_amdgcn_readfirstlane(t >> 6);
    int l = t & 63;
    int m16 = l & 15, quad = l >> 4;
    fv4 acc[7];
#pragma unroll
    for (int nt = 0; nt < 7; nt++) acc[nt] = (fv4){0.f, 0.f, 0.f, 0.f};
    const ushort* arow = Al + (w * 16 + m16) * APITCH;
#pragma unroll
    for (int kk = 0; kk < 4; kk++) {
        int kb = kk * 32 + quad * 8;
        bfv8 a = *(const bfv8*)(arow + kb);
#pragma unroll
        for (int nt = 0; nt < 7; nt++) {
            bfv8 b = *(const bfv8*)(Bt + (nt * 16 + m16) * APITCH + kb);
            acc[nt] = __builtin_amdgcn_mfma_f32_16x16x32_bf16(a, b, acc[nt], 0, 0, 0);
        }
    }
    __syncthreads();
    float* Ep = (float*)smem;
#pragma unroll
    for (int nt = 0; nt < 7; nt++) {
        int n = nt * 16 + m16;
        if (n < 100) {
#pragma unroll
            for (int rix = 0; rix < 4; rix++)
                Ep[(w * 16 + quad * 4 + rix) * 101 + n] = acc[nt][rix];
        }
    }
    __syncthreads();
#pragma unroll
    for (int i = 0; i < 13; i++) {
        int p = i * 256 + t;
        if (p < 3200) {
            int rr = p / 50, cc = 2 * (p % 50);
            int row = row0 + rr;
            if (row < NN) {
                float v0 = Ep[rr * 101 + cc], v1 = Ep[rr * 101 + cc + 1];
                *(uint*)(z1bf + (size_t)row * 128 + cc) = packbf2(v0, v1);
            }
        }
    }
}

// A1: per-(bucket,block) histogram
__global__ __launch_bounds__(256) void k_csrA1(const int* __restrict__ dst,
                                               int* __restrict__ pbcount) {
    __shared__ int h[NB];
    int t = threadIdx.x, blk = blockIdx.x;
    for (int i = t; i < NB; i += 256) h[i] = 0;
    __syncthreads();
    int e0 = blk * EPB + t;
#pragma unroll
    for (int i = 0; i < 8; i++) {
        int e = e0 + i * 256;
        if (e < NE) atomicAdd(&h[dst[e] >> 8], 1);
    }
    __syncthreads();
    for (int i = t; i < NB; i += 256) pbcount[i * NBLK + blk] = h[i];
}

// S1: per-bucket exclusive scan over 782 blocks (in-place) + bucket totals
__global__ __launch_bounds__(1024) void k_csrS1(int* __restrict__ pbcount,
                                                int* __restrict__ btot) {
    __shared__ int s[1024];
    int t = threadIdx.x, b = blockIdx.x;
    int v = (t < NBLK) ? pbcount[b * NBLK + t] : 0;
    s[t] = v;
    __syncthreads();
    for (int off = 1; off < 1024; off <<= 1) {
        int x = (t >= off) ? s[t - off] : 0;
        __syncthreads();
        s[t] += x;
        __syncthreads();
    }
    if (t < NBLK) pbcount[b * NBLK + t] = s[t] - v;
    if (t == 1023) btot[b] = s[t];
}

// A2: in-block ebase scan of btot; append packed edges; blk 0 publishes ebase
__global__ __launch_bounds__(256) void k_csrA2(const int* __restrict__ src,
                                               const int* __restrict__ dst,
                                               const int* __restrict__ pbexcl,
                                               const int* __restrict__ btot,
                                               int* __restrict__ ebase_g,
                                               uint* __restrict__ gbuf) {
    __shared__ int cur[NB];
    __shared__ int sa[512], sb[512];
    int t = threadIdx.x, blk = blockIdx.x;
    int o0 = (t < NB) ? btot[t] : 0;
    int o1 = (t + 256 < NB) ? btot[t + 256] : 0;
    sa[t] = o0; sa[t + 256] = o1;
    __syncthreads();
    int* sp = sa; int* dp = sb;
    for (int off = 1; off < 512; off <<= 1) {
        dp[t] = sp[t] + ((t >= off) ? sp[t - off] : 0);
        int i2 = t + 256;
        dp[i2] = sp[i2] + ((i2 >= off) ? sp[i2 - off] : 0);
        __syncthreads();
        int* tmp = sp; sp = dp; dp = tmp;
    }
    if (t < NB)       cur[t]       = (sp[t] - o0) + pbexcl[t * NBLK + blk];
    if (t + 256 < NB) cur[t + 256] = (sp[t + 256] - o1) + pbexcl[(t + 256) * NBLK + blk];
    if (blk == 0) {
        if (t < NB)       ebase_g[t]       = sp[t] - o0;
        if (t + 256 < NB) ebase_g[t + 256] = sp[t + 256] - o1;
        if (t == 0)       ebase_g[NB]      = sp[NB - 1];
    }
    __syncthreads();
    int e0 = blk * EPB + t;
#pragma unroll
    for (int i = 0; i < 8; i++) {
        int e = e0 + i * 256;
        if (e < NE) {
            int d = dst[e];
            int b = d >> 8;
            int pos = atomicAdd(&cur[b], 1);
            gbuf[pos] = (uint)src[e] | ((uint)(d & 255) << 17);
        }
    }
}

// B: per-bucket LDS counting sort by local dst -> deg, offs, srcS
__global__ __launch_bounds__(256) void k_csrB(const uint* __restrict__ gbuf,
                                              const int* __restrict__ ebase,
                                              int* __restrict__ deg,
                                              int* __restrict__ offs,
                                              int* __restrict__ srcS) {
    __shared__ uint raw[RAWCAP];
    __shared__ int srt[RAWCAP];
    __shared__ int pref[256], cur[256];
    int t = threadIdx.x, b = blockIdx.x;
    int e0 = ebase[b], e1 = ebase[b + 1];
    int cnt = e1 - e0; if (cnt > RAWCAP) cnt = RAWCAP;
    cur[t] = 0;
    for (int i = t; i < cnt; i += 256) raw[i] = gbuf[e0 + i];
    __syncthreads();
    for (int i = t; i < cnt; i += 256) atomicAdd(&cur[raw[i] >> 17], 1);
    __syncthreads();
    int v = cur[t];
    pref[t] = v;
    __syncthreads();
    for (int off = 1; off < 256; off <<= 1) {
        int x = (t >= off) ? pref[t - off] : 0;
        __syncthreads();
        pref[t] += x;
        __syncthreads();
    }
    int excl = pref[t] - v;
    int node = b * 256 + t;
    if (node < NN) { deg[node] = v; offs[node] = e0 + excl; }
    cur[t] = excl;
    __syncthreads();
    for (int i = t; i < cnt; i += 256) {
        uint p = raw[i];
        int lpos = atomicAdd(&cur[p >> 17], 1);
        srt[lpos] = (int)(p & 0x1FFFFu);
    }
    __syncthreads();
    for (int i = t; i < cnt; i += 256) srcS[e0 + i] = srt[i];
}

// ------- u1(bf16) = z1 + gather-sum; wave/node, unroll 8 --------
__global__ __launch_bounds__(256) void k_agg1(const ushort* __restrict__ z1bf,
                                              const int* __restrict__ offs,
                                              const int* __restrict__ deg,
                                              const int* __restrict__ srcS,
                                              ushort* __restrict__ u1b) {
    int wq = __builtin_amdgcn_readfirstlane(threadIdx.x >> 6);
    int l = threadIdx.x & 63;
    int n = blockIdx.x * 4 + wq;
    if (n >= NN) return;
    int d = deg[n], base = offs[n];
    bool act = l < 50;
    const ushort* zc = z1bf + 2 * l;
    float a0 = 0.f, a1 = 0.f, b0 = 0.f, b1 = 0.f;
    float c0 = 0.f, c1 = 0.f, e0 = 0.f, e1 = 0.f;
    int i = 0;
    for (; i + 8 <= d; i += 8) {
        int s0 = srcS[base + i],     s1 = srcS[base + i + 1];
        int s2 = srcS[base + i + 2], s3 = srcS[base + i + 3];
        int s4 = srcS[base + i + 4], s5 = srcS[base + i + 5];
        int s6 = srcS[base + i + 6], s7 = srcS[base + i + 7];
        if (act) {
            uint x0 = *(const uint*)(zc + (size_t)s0 * 128);
            uint x1 = *(const uint*)(zc + (size_t)s1 * 128);
            uint x2 = *(const uint*)(zc + (size_t)s2 * 128);
            uint x3 = *(const uint*)(zc + (size_t)s3 * 128);
            uint x4 = *(const uint*)(zc + (size_t)s4 * 128);
            uint x5 = *(const uint*)(zc + (size_t)s5 * 128);
            uint x6 = *(const uint*)(zc + (size_t)s6 * 128);
            uint x7 = *(const uint*)(zc + (size_t)s7 * 128);
            a0 += bflo(x0); a1 += bfhi(x0);
            b0 += bflo(x1); b1 += bfhi(x1);
            c0 += bflo(x2); c1 += bfhi(x2);
            e0 += bflo(x3); e1 += bfhi(x3);
            a0 += bflo(x4); a1 += bfhi(x4);
            b0 += bflo(x5); b1 += bfhi(x5);
            c0 += bflo(x6); c1 += bfhi(x6);
            e0 += bflo(x7); e1 += bfhi(x7);
        }
    }
    for (; i + 2 <= d; i += 2) {
        int s0 = srcS[base + i], s1 = srcS[base + i + 1];
        if (act) {
            uint x0 = *(const uint*)(zc + (size_t)s0 * 128);
            uint x1 = *(const uint*)(zc + (size_t)s1 * 128);
            a0 += bflo(x0); a1 += bfhi(x0);
            b0 += bflo(x1); b1 += bfhi(x1);
        }
    }
    if (i < d) {
        int s0 = srcS[base + i];
        if (act) {
            uint x0 = *(const uint*)(zc + (size_t)s0 * 128);
            a0 += bflo(x0); a1 += bfhi(x0);
        }
    }
    if (act) {
        uint xs = *(const uint*)(zc + (size_t)n * 128);
        float r0 = (a0 + b0) + (c0 + e0) + bflo(xs);
        float r1 = (a1 + b1) + (c1 + e1) + bfhi(xs);
        *(uint*)(u1b + (size_t)n * 100 + 2 * l) = packbf2(r0, r1);
    }
}

// ----- BN stats over u1 (bf16 in, 500 block partials) -----
__global__ __launch_bounds__(256) void k_bnstat100(const ushort* __restrict__ u1b,
                                                   float* __restrict__ pb) {
    __shared__ float ls[10][100], lq[10][100];
    int t = threadIdx.x;
    int r0 = blockIdx.x * 200;
    int r1 = r0 + 200; if (r1 > NN) r1 = NN;
    if (t < 250) {
        int sub = t / 25, q = t % 25;
        float4 S = make_float4(0, 0, 0, 0), Q = make_float4(0, 0, 0, 0);
        for (int r = r0 + sub; r < r1; r += 10) {
            uint2 x = *(const uint2*)(u1b + (size_t)r * 100 + 4 * q);
            float v0 = bflo(x.x), v1 = bfhi(x.x), v2 = bflo(x.y), v3 = bfhi(x.y);
            S.x += v0; S.y += v1; S.z += v2; S.w += v3;
            Q.x = fmaf(v0, v0, Q.x); Q.y = fmaf(v1, v1, Q.y);
            Q.z = fmaf(v2, v2, Q.z); Q.w = fmaf(v3, v3, Q.w);
        }
        ls[sub][4 * q + 0] = S.x; ls[sub][4 * q + 1] = S.y;
        ls[sub][4 * q + 2] = S.z; ls[sub][4 * q + 3] = S.w;
        lq[sub][4 * q + 0] = Q.x; lq[sub][4 * q + 1] = Q.y;
        lq[sub][4 * q + 2] = Q.z; lq[sub][4 * q + 3] = Q.w;
    }
    __syncthreads();
    if (t < 100) {
        float S = 0.f, Q = 0.f;
#pragma unroll
        for (int s = 0; s < 10; s++) { S += ls[s][t]; Q += lq[s][t]; }
        pb[blockIdx.x * 200 + t] = S;
        pb[blockIdx.x * 200 + 100 + t] = Q;
    }
}

// fold 500 pb1 records -> 25 (coalesced LDS load, strided LDS reduce)
__global__ __launch_bounds__(256) void k_fold100(const float* __restrict__ pb,
                                                 float* __restrict__ pbf) {
    __shared__ float ls[4000];
    int t = threadIdx.x, b = blockIdx.x;
    for (int i = t; i < 4000; i += 256) ls[i] = pb[b * 4000 + i];
    __syncthreads();
    if (t < 200) {
        float S = 0.f;
#pragma unroll
        for (int j = 0; j < 20; j++) S += ls[j * 200 + t];
        pbf[b * 200 + t] = S;
    }
}

__global__ __launch_bounds__(512) void k_bnfin100(const float* __restrict__ pbf,
                                                  const float* __restrict__ gamma,
                                                  const float* __restrict__ beta,
                                                  float* __restrict__ sc,
                                                  float* __restrict__ sh) {
    __shared__ float ls[4][100], lq[4][100];
    int t = threadIdx.x;
    if (t < 400) {
        int sub = t / 100, c = t % 100;
        float S = 0.f, Q = 0.f;
        for (int b = sub; b < NF1; b += 4) {
            S += pbf[b * 200 + c];
            Q += pbf[b * 200 + 100 + c];
        }
        ls[sub][c] = S; lq[sub][c] = Q;
    }
    __syncthreads();
    if (t < 100) {
        float S = ls[0][t] + ls[1][t] + ls[2][t] + ls[3][t];
        float Q = lq[0][t] + lq[1][t] + lq[2][t] + lq[3][t];
        float mean = S * (1.f / NN);
        float var = Q * (1.f / NN) - mean * mean;
        float inv = rsqrtf(var + BN_EPS);
        float s = gamma[t] * inv;
        sc[t] = s;
        sh[t] = beta[t] - mean * s;
    }
}

// ------ fused: relu(bn1(u1)) @ g1_W2 + b2 -> relu -> @ g2_W1 = z2bf ----------
__global__ __launch_bounds__(256) void k_m2(const ushort* __restrict__ u1b,
                                            const float* __restrict__ sc,
                                            const float* __restrict__ sh,
                                            const float* __restrict__ W2,   // [100][100]
                                            const float* __restrict__ b2,
                                            const float* __restrict__ W1p,  // [100][20]
                                            ushort* __restrict__ z2bf) {
    __shared__ float Xs[100 * 65];
    int t = threadIdx.x;
    int row0 = blockIdx.x * 64;
#pragma unroll
    for (int i = 0; i < 13; i++) {
        int p = i * 256 + t;
        if (p < 3200) {
            int r = p / 50, c = 2 * (p % 50);
            int row = row0 + r; if (row >= NN) row = NN - 1;
            uint x = *(const uint*)(u1b + (size_t)row * 100 + c);
            Xs[c * 65 + r] = fmaxf(bflo(x) * sc[c] + sh[c], 0.f);
            Xs[(c + 1) * 65 + r] = fmaxf(bfhi(x) * sc[c + 1] + sh[c + 1], 0.f);
        }
    }
    __syncthreads();
    int cg = __builtin_amdgcn_readfirstlane(t >> 6);
    int r = t & 63;
    int j0 = cg * 25;
    float H[25];
#pragma unroll
    for (int m = 0; m < 25; m++) H[m] = 0.f;
    for (int k = 0; k < D1; k++) {
        float a = Xs[k * 65 + r];
        const float* wr = W2 + k * D1 + j0;  // wave-uniform -> s_load
#pragma unroll
        for (int m = 0; m < 25; m++) H[m] = fmaf(a, wr[m], H[m]);
    }
#pragma unroll
    for (int m = 0; m < 25; m++) H[m] = fmaxf(H[m] + b2[j0 + m], 0.f);
    float pz[20];
#pragma unroll
    for (int c = 0; c < 20; c++) pz[c] = 0.f;
#pragma unroll
    for (int m = 0; m < 25; m++) {
        const float* wp = W1p + (j0 + m) * D2;  // wave-uniform -> s_load
#pragma unroll
        for (int c = 0; c < 20; c++) pz[c] = fmaf(H[m], wp[c], pz[c]);
    }
    __syncthreads();
    float* red = Xs;
#pragma unroll
    for (int c = 0; c < 20; c++) red[t * 20 + c] = pz[c];
    __syncthreads();
#pragma unroll
    for (int i = 0; i < 3; i++) {
        int p = i * 256 + t;
        if (p < 640) {
            int rr = p / 10, c2 = 2 * (p % 10);
            int row = row0 + rr;
            if (row < NN) {
                float v0 = red[rr * 20 + c2] + red[(64 + rr) * 20 + c2] +
                           red[(128 + rr) * 20 + c2] + red[(192 + rr) * 20 + c2];
                float v1 = red[rr * 20 + c2 + 1] + red[(64 + rr) * 20 + c2 + 1] +
                           red[(128 + rr) * 20 + c2 + 1] + red[(192 + rr) * 20 + c2 + 1];
                *(uint*)(z2bf + (size_t)row * 32 + c2) = packbf2(v0, v1);
            }
        }
    }
}

// ------- u2 = z2 + gather-sum (+ fused BN2 block partials) ---------
__global__ __launch_bounds__(256) void k_agg2(const ushort* __restrict__ z2bf,
                                              const int* __restrict__ offs,
                                              const int* __restrict__ deg,
                                              const int* __restrict__ srcS,
                                              float* __restrict__ u2,
                                              float* __restrict__ pb) {
    __shared__ float ls[500], lq[500];
    int t = threadIdx.x;
    int n = blockIdx.x * 25 + t / 10;
    int c2 = 2 * (t % 10);
    float r0 = 0.f, r1 = 0.f;
    if (t < 250 && n < NN) {
        int d = deg[n], base = offs[n];
        const ushort* zc = z2bf + c2;
        float a0 = 0.f, a1 = 0.f, b0 = 0.f, b1 = 0.f;
        int i = 0;
        for (; i + 2 <= d; i += 2) {
            uint x0 = *(const uint*)(zc + (size_t)srcS[base + i] * 32);
            uint x1 = *(const uint*)(zc + (size_t)srcS[base + i + 1] * 32);
            a0 += bflo(x0); a1 += bfhi(x0);
            b0 += bflo(x1); b1 += bfhi(x1);
        }
        if (i < d) {
            uint x0 = *(const uint*)(zc + (size_t)srcS[base + i] * 32);
            a0 += bflo(x0); a1 += bfhi(x0);
        }
        uint xs = *(const uint*)(zc + (size_t)n * 32);
        r0 = a0 + b0 + bflo(xs);
        r1 = a1 + b1 + bfhi(xs);
        *(float2*)(u2 + (size_t)n * D2 + c2) = make_float2(r0, r1);
    }
    if (t < 250) {
        int idx = (t / 10) * 20 + c2;
        ls[idx] = r0;     lq[idx] = r0 * r0;
        ls[idx + 1] = r1; lq[idx + 1] = r1 * r1;
    }
    __syncthreads();
    if (t < 20) {
        float S = 0.f, Q = 0.f;
#pragma unroll
        for (int j = 0; j < 25; j++) { S += ls[j * 20 + t]; Q += lq[j * 20 + t]; }
        pb[blockIdx.x * 40 + t] = S;
        pb[blockIdx.x * 40 + 20 + t] = Q;
    }
}

// fold 4000 pb2 records -> 40 (coalesced LDS load, strided LDS reduce)
__global__ __launch_bounds__(256) void k_fold20(const float* __restrict__ pb,
                                                float* __restrict__ pbf) {
    __shared__ float ls[4000];
    int t = threadIdx.x, b = blockIdx.x;
    for (int i = t; i < 4000; i += 256) ls[i] = pb[b * 4000 + i];
    __syncthreads();
    if (t < 40) {
        float S = 0.f;
#pragma unroll
        for (int j = 0; j < 100; j++) S += ls[j * 40 + t];
        pbf[b * 40 + t] = S;
    }
}

__global__ __launch_bounds__(512) void k_bnfin20(const float* __restrict__ pbf,
                                                 const float* __restrict__ gamma,
                                                 const float* __restrict__ beta,
                                                 float* __restrict__ sc,
                                                 float* __restrict__ sh) {
    __shared__ float ls[25][20], lq[25][20];
    int t = threadIdx.x;
    if (t < 500) {
        int sub = t / 20, c = t % 20;
        float S = 0.f, Q = 0.f;
        for (int b = sub; b < NF2; b += 25) {
            S += pbf[b * 40 + c];
            Q += pbf[b * 40 + 20 + c];
        }
        ls[sub][c] = S; lq[sub][c] = Q;
    }
    __syncthreads();
    if (t < 20) {
        float S = 0.f, Q = 0.f;
#pragma unroll
        for (int s = 0; s < 25; s++) { S += ls[s][t]; Q += lq[s][t]; }
        float mean = S * (1.f / NN);
        float var = Q * (1.f / NN) - mean * mean;
        float inv = rsqrtf(var + BN_EPS);
        float s = gamma[t] * inv;
        sc[t] = s;
        sh[t] = beta[t] - mean * s;
    }
}

// ------ fused: relu(bn2(u2)) @ g2_W2 + b2 -> relu = h2 ------------
__global__ __launch_bounds__(256) void k_m3(const float* __restrict__ u2,
                                            const float* __restrict__ sc,
                                            const float* __restrict__ sh,
                                            const float* __restrict__ W2p,  // [20][20]
                                            const float* __restrict__ b2p,
                                            float* __restrict__ h2) {
    int row = blockIdx.x * 256 + threadIdx.x;
    if (row >= NN) return;
    float ya[20];
    const float4* up = (const float4*)(u2 + (size_t)row * D2);
#pragma unroll
    for (int i = 0; i < 5; i++) {
        float4 v = up[i];
        float4 S = *(const float4*)(sc + 4 * i);
        float4 H = *(const float4*)(sh + 4 * i);
        ya[4 * i + 0] = fmaxf(v.x * S.x + H.x, 0.f);
        ya[4 * i + 1] = fmaxf(v.y * S.y + H.y, 0.f);
        ya[4 * i + 2] = fmaxf(v.z * S.z + H.z, 0.f);
        ya[4 * i + 3] = fmaxf(v.w * S.w + H.w, 0.f);
    }
    float hrow[D2];
#pragma unroll
    for (int j = 0; j < D2; j++) {
        float h = b2p[j];
#pragma unroll
        for (int k = 0; k < D2; k++) h = fmaf(ya[k], W2p[k * D2 + j], h);
        hrow[j] = fmaxf(h, 0.f);
    }
    float* hr = h2 + (size_t)row * D2;
#pragma unroll
    for (int c = 0; c < D2; c += 4) {
        float4 o; o.x = hrow[c]; o.y = hrow[c + 1]; o.z = hrow[c + 2]; o.w = hrow[c + 3];
        *(float4*)(hr + c) = o;
    }
}

// ---- pool: wave/graph, bounds via binary search on sorted n2g ----
__global__ __launch_bounds__(256) void k_pool(const float* __restrict__ h2,
                                              const int* __restrict__ n2g,
                                              float* __restrict__ hg) {
    int wq = __builtin_amdgcn_readfirstlane(threadIdx.x >> 6);
    int l = threadIdx.x & 63;
    int g = blockIdx.x * 4 + wq;
    if (g >= NG) return;
    int lo = 0, hi = NN;
    while (lo < hi) { int mid = (lo + hi) >> 1; if (n2g[mid] < g) lo = mid + 1; else hi = mid; }
    int s0 = lo;
    hi = NN;
    while (lo < hi) { int mid = (lo + hi) >> 1; if (n2g[mid] < g + 1) lo = mid + 1; else hi = mid; }
    int s1 = lo;
    float a = 0.f;
    if (l < 60) {
        int rg = l / 20, c = l % 20;
        for (int n = s0 + rg; n < s1; n += 3) a += h2[(size_t)n * D2 + c];
    }
    float v1 = __shfl(a, l + 20, 64);
    float v2 = __shfl(a, l + 40, 64);
    if (l < 20) {
        float cnt = (float)(s1 - s0);
        hg[g * D2 + l] = (a + v1 + v2) / fmaxf(cnt, 1.f);
    }
}

// ---------------- a1 = kron(hg, self_feat) @ fc1_W ----------------
__global__ void k_head1(const float* __restrict__ hg, const float* __restrict__ sf,
                        const float* __restrict__ fc1W, float* __restrict__ a1) {
    int b = blockIdx.x * 8 + threadIdx.x / 32;
    int c = threadIdx.x % 32;
    if (b >= NG) return;
    const float* hgb = hg + b * D2;
    const float* sfb = sf + b * DSELF;
    float acc = 0.f;
    for (int i = 0; i < D2; i++) {
        float hi = hgb[i];
#pragma unroll
        for (int j = 0; j < DSELF; j++)
            acc += hi * sfb[j] * fc1W[(i * DSELF + j) * 32 + c];
    }
    a1[b * 32 + c] = acc;
}

// ---------------- single-block head: bn1->relu->fc2->bn2->relu->fc3 ----------
__global__ __launch_bounds__(1024) void k_head2(
    const float* __restrict__ a1, const float* __restrict__ g1,
    const float* __restrict__ be1, const float* __restrict__ fc2W,
    const float* __restrict__ g2, const float* __restrict__ be2,
    const float* __restrict__ fc3W, const float* __restrict__ fc3b,
    float* __restrict__ out) {
    int t = threadIdx.x;
    int lane = t & 63, w = t >> 6;
    __shared__ float s1[16][32], s2[16][32];
    __shared__ float sc[32], sh[32], sc2[8], sh2[8];
    float x[32];
    const float4* ap = (const float4*)(a1 + t * 32);
#pragma unroll
    for (int i = 0; i < 8; i++) {
        float4 v = ap[i];
        x[4 * i] = v.x; x[4 * i + 1] = v.y; x[4 * i + 2] = v.z; x[4 * i + 3] = v.w;
    }
#pragma unroll
    for (int c = 0; c < 32; c++) {
        float v = x[c], q = v * v;
        for (int o = 32; o > 0; o >>= 1) {
            v += __shfl_down(v, o, 64);
            q += __shfl_down(q, o, 64);
        }
        if (lane == 0) { s1[w][c] = v; s2[w][c] = q; }
    }
    __syncthreads();
    if (t < 32) {
        float s = 0.f, q = 0.f;
        for (int ww = 0; ww < 16; ww++) { s += s1[ww][t]; q += s2[ww][t]; }
        float mean = s * (1.f / NG);
        float var = q * (1.f / NG) - mean * mean;
        float inv = rsqrtf(var + BN_EPS);
        float scl = g1[t] * inv;
        sc[t] = scl;
        sh[t] = be1[t] - mean * scl;
    }
    __syncthreads();
#pragma unroll
    for (int c = 0; c < 32; c++) x[c] = fmaxf(x[c] * sc[c] + sh[c], 0.f);
    float y[8];
#pragma unroll
    for (int p = 0; p < 8; p++) {
        float a = 0.f;
#pragma unroll
        for (int c = 0; c < 32; c++) a += x[c] * fc2W[c * 8 + p];
        y[p] = a;
    }
    __syncthreads();
#pragma unroll
    for (int p = 0; p < 8; p++) {
        float v = y[p], q = v * v;
        for (int o = 32; o > 0; o >>= 1) {
            v += __shfl_down(v, o, 64);
            q += __shfl_down(q, o, 64);
        }
        if (lane == 0) { s1[w][p] = v; s2[w][p] = q; }
    }
    __syncthreads();
    if (t < 8) {
        float s = 0.f, q = 0.f;
        for (int ww = 0; ww < 16; ww++) { s += s1[ww][t]; q += s2[ww][t]; }
        float mean = s * (1.f / NG);
        float var = q * (1.f / NG) - mean * mean;
        float inv = rsqrtf(var + BN_EPS);
        float scl = g2[t] * inv;
        sc2[t] = scl;
        sh2[t] = be2[t] - mean * scl;
    }
    __syncthreads();
    float o = fc3b[0];
#pragma unroll
    for (int p = 0; p < 8; p++) {
        float yy = fmaxf(y[p] * sc2[p] + sh2[p], 0.f);
        o += yy * fc3W[p];
    }
    out[t] = o;
}

extern "C" void kernel_launch(void* const* d_in, const int* in_sizes, int n_in,
                              void* d_out, int out_size, void* d_ws, size_t ws_size,
                              hipStream_t stream) {
    const float* feat    = (const float*)d_in[0];
    const float* sf      = (const float*)d_in[1];
    const int*   esrc    = (const int*)d_in[2];
    const int*   edst    = (const int*)d_in[3];
    const int*   n2g     = (const int*)d_in[4];
    const float* g1W1    = (const float*)d_in[5];
    const float* g1gam   = (const float*)d_in[7];
    const float* g1bet   = (const float*)d_in[8];
    const float* g1W2    = (const float*)d_in[9];
    const float* g1b2    = (const float*)d_in[10];
    const float* g2W1    = (const float*)d_in[11];
    const float* g2gam   = (const float*)d_in[13];
    const float* g2bet   = (const float*)d_in[14];
    const float* g2W2    = (const float*)d_in[15];
    const float* g2b2    = (const float*)d_in[16];
    const float* fc1W    = (const float*)d_in[17];
    const float* hbn1g   = (const float*)d_in[19];
    const float* hbn1b   = (const float*)d_in[20];
    const float* fc2W    = (const float*)d_in[21];
    const float* hbn2g   = (const float*)d_in[23];
    const float* hbn2b   = (const float*)d_in[24];
    const float* fc3W    = (const float*)d_in[25];
    const float* fc3b    = (const float*)d_in[26];
    float* out = (float*)d_out;

    char* w = (char*)d_ws;
    size_t off = 0;
    auto alloc = [&](size_t bytes) -> char* {
        char* p = w + off;
        off += (bytes + 15) & ~(size_t)15;
        return p;
    };
    char* regA = alloc((size_t)NN * 128 * 2);
    ushort* z1bf = (ushort*)regA;
    ushort* z2bf = (ushort*)regA;
    float*  u2   = (float*)(regA + 6400000);
    float*  h2   = (float*)(regA + 14400000);
    ushort* u1b  = (ushort*)alloc((size_t)NN * 100 * 2);
    int*   pbcnt = (int*)alloc((size_t)NB * NBLK * 4);
    int*   btot  = (int*)alloc(NB * 4);
    int*   ebase = (int*)alloc((NB + 1) * 4);
    uint*  gbuf  = (uint*)alloc((size_t)NE * 4);
    int*   deg   = (int*)alloc(NN * 4);
    int*   offs  = (int*)alloc(NN * 4);
    int*   srcS  = (int*)alloc((size_t)NE * 4);
    float* pb1   = (float*)alloc(500 * 200 * 4);
    float* pb1f  = (float*)alloc(NF1 * 200 * 4);
    float* pb2   = (float*)alloc((size_t)NAGG2 * 40 * 4);
    float* pb2f  = (float*)alloc(NF2 * 40 * 4);
    float* sc1   = (float*)alloc(D1 * 4);
    float* sh1   = (float*)alloc(D1 * 4);
    float* sc2   = (float*)alloc(D2 * 4);
    float* sh2   = (float*)alloc(D2 * 4);
    float* hg    = (float*)alloc(NG * D2 * 4);
    float* a1    = (float*)alloc(NG * 32 * 4);
    (void)in_sizes; (void)n_in; (void)out_size; (void)ws_size;

    k_gemm1<<<(NN + 63) / 64, 256, 0, stream>>>(feat, g1W1, z1bf);

    k_csrA1<<<NBLK, 256, 0, stream>>>(edst, pbcnt);
    k_csrS1<<<NB, 1024, 0, stream>>>(pbcnt, btot);
    k_csrA2<<<NBLK, 256, 0, stream>>>(esrc, edst, pbcnt, btot, ebase, gbuf);
    k_csrB<<<NB, 256, 0, stream>>>(gbuf, ebase, deg, offs, srcS);

    k_agg1<<<(NN + 3) / 4, 256, 0, stream>>>(z1bf, offs, deg, srcS, u1b);
    k_bnstat100<<<500, 256, 0, stream>>>(u1b, pb1);
    k_fold100<<<NF1, 256, 0, stream>>>(pb1, pb1f);
    k_bnfin100<<<1, 512, 0, stream>>>(pb1f, g1gam, g1bet, sc1, sh1);
    k_m2<<<(NN + 63) / 64, 256, 0, stream>>>(u1b, sc1, sh1, g1W2, g1b2, g2W1, z2bf);

    k_agg2<<<NAGG2, 256, 0, stream>>>(z2bf, offs, deg, srcS, u2, pb2);
    k_fold20<<<NF2, 256, 0, stream>>>(pb2, pb2f);
    k_bnfin20<<<1, 512, 0, stream>>>(pb2f, g2gam, g2bet, sc2, sh2);
    k_m3<<<(NN + 255) / 256, 256, 0, stream>>>(u2, sc2, sh2, g2W2, g2b2, h2);

    k_pool<<<(NG + 3) / 4, 256, 0, stream>>>(h2, n2g, hg);
    k_head1<<<NG / 8, 256, 0, stream>>>(hg, sf, fc1W, a1);
    k_head2<<<1, 1024, 0, stream>>>(a1, hbn1g, hbn1b, fc2W, hbn2g, hbn2b, fc3W, fc3b, out);
}